// Round 3
// baseline (49.268 us; speedup 1.0000x reference)
//
#include <hip/hip_runtime.h>
#include <hip/hip_bf16.h>

typedef __attribute__((ext_vector_type(8))) short short8;
typedef __attribute__((ext_vector_type(4))) float f32x4;
typedef __attribute__((ext_vector_type(2))) float f32x2;

// fp32 -> bf16 round-to-nearest-even (finite inputs)
__device__ __forceinline__ unsigned short f2bf(float f) {
    union { float f; unsigned int u; } v; v.f = f;
    unsigned int u = v.u;
    u = (u + 0x7FFFu + ((u >> 16) & 1u)) >> 16;
    return (unsigned short)u;
}

// ---------------------------------------------------------------------------
// Kernel 1: x[b][c][h][w] f32  ->  xt[h][w][c][b] bf16
// ---------------------------------------------------------------------------
__global__ __launch_bounds__(256) void k_xt(const float* __restrict__ x,
                                            unsigned short* __restrict__ xt) {
    const int h  = blockIdx.x;   // 0..31
    const int cg = blockIdx.y;   // 0..7
    const int t  = threadIdx.x;
    __shared__ unsigned short L[32 * 520];

    #pragma unroll
    for (int i = 0; i < 16; ++i) {
        int s   = t + i * 256;
        int row = s >> 3;
        int wq  = s & 7;
        int b = row >> 3, c = row & 7;
        const f32x4 v = *(const f32x4*)(x + (((size_t)(b * 64 + cg * 8 + c) * 32 + h) * 32 + wq * 4));
        int base = c * 64 + b;
        L[(wq * 4 + 0) * 520 + base] = f2bf(v[0]);
        L[(wq * 4 + 1) * 520 + base] = f2bf(v[1]);
        L[(wq * 4 + 2) * 520 + base] = f2bf(v[2]);
        L[(wq * 4 + 3) * 520 + base] = f2bf(v[3]);
    }
    __syncthreads();
    #pragma unroll
    for (int i = 0; i < 8; ++i) {
        int s  = t + i * 256;
        int w  = s >> 6;
        int ch = s & 63;
        short8 v = *(const short8*)&L[w * 520 + ch * 8];
        *(short8*)(xt + (((size_t)(h * 32 + w) * 64 + cg * 8) * 64 + ch * 8)) = v;
    }
}

// ---------------------------------------------------------------------------
// Fused kernel: per-location GEMM + direct output write.
// 512 blocks, each owns 2 consecutive l's and the full 64(b) x 64(o) tile.
// 18-round flattened software pipeline (double-buffered LDS, raw barriers,
// loads stay in flight). After the GEMMs, the A/B LDS is reused as an f32
// staging buffer to emit coalesced out[b*64+o][l0..l0+1] stores.
// ---------------------------------------------------------------------------
__global__ __launch_bounds__(256) void k_fused(const float* __restrict__ wgt,
                                               const unsigned short* __restrict__ xt,
                                               const float* __restrict__ bias,
                                               float* __restrict__ out) {
    const int bid  = blockIdx.x;
    const int tile = (bid & 7) * 64 + (bid >> 3);   // bijective XCD swizzle (512 % 8 == 0)
    const int l0   = tile * 2;
    const int oh   = l0 >> 5;
    const int ow0  = l0 & 31;                        // even, so l0/l0+1 share oh
    const int t    = threadIdx.x;
    const int wave = t >> 6, lane = t & 63;
    const int wm = wave >> 1, wn = wave & 1;

    // S[0..1] = A double buffer, S[2..3] = B double buffer ([64][72] ushort each).
    // Reused after the k-loop as an f32 out-staging buffer (9216 floats >= 8192).
    __shared__ unsigned short S[4][64 * 72];

    f32x4 acc[2][2][2];  // [li][i][j]
    #pragma unroll
    for (int li = 0; li < 2; ++li)
        #pragma unroll
        for (int i = 0; i < 2; ++i)
            #pragma unroll
            for (int j = 0; j < 2; ++j)
                acc[li][i][j] = (f32x4){0.f, 0.f, 0.f, 0.f};

    const int b0 = wave * 16;
    const int o  = t >> 2, kp = t & 3;
    const float* bbase = wgt + (size_t)l0 * (64 * 576) + o * 576 + kp * 16;

    auto loadA = [&](int li, int kt, short8& va, short8& vb) {
        int kk = kt * 64 + lane;      // 0..575
        int c  = kk / 9;
        int r  = kk - c * 9;
        int kh = r / 3;
        int kw = r - kh * 3;
        int hh = oh + kh - 1;
        int ww = ow0 + li + kw - 1;
        va = (short8){0,0,0,0,0,0,0,0};
        vb = (short8){0,0,0,0,0,0,0,0};
        if ((unsigned)hh < 32u && (unsigned)ww < 32u) {
            const unsigned short* src = xt + (((size_t)(hh * 32 + ww) * 64 + c) * 64 + b0);
            va = *(const short8*)src;
            vb = *(const short8*)(src + 8);
        }
    };
    auto loadB = [&](int li, int kt, f32x4& w0, f32x4& w1, f32x4& w2, f32x4& w3) {
        const f32x4* bp = (const f32x4*)(bbase + (size_t)li * 36864 + kt * 64);
        w0 = bp[0]; w1 = bp[1]; w2 = bp[2]; w3 = bp[3];
    };

    short8 cA0, cA1;
    short8 nA0 = (short8){0,0,0,0,0,0,0,0}, nA1 = nA0;
    f32x4 cB0, cB1, cB2, cB3;
    f32x4 nB0 = (f32x4){0,0,0,0}, nB1 = nB0, nB2 = nB0, nB3 = nB0;

    loadA(0, 0, cA0, cA1);
    loadB(0, 0, cB0, cB1, cB2, cB3);

    #pragma unroll
    for (int li = 0; li < 2; ++li) {
        for (int kt = 0; kt < 9; ++kt) {
            const int p = (li + kt) & 1;
            // issue next round's loads FIRST — they stay in flight across the barrier
            if (!(li == 1 && kt == 8)) {
                int lin = (kt == 8) ? li + 1 : li;
                int ktn = (kt == 8) ? 0 : kt + 1;
                loadA(lin, ktn, nA0, nA1);
                loadB(lin, ktn, nB0, nB1, nB2, nB3);
            }
            // stage A ([b][k] b16 scatter)
            #pragma unroll
            for (int j = 0; j < 8; ++j) S[p][(b0 + j) * 72 + lane] = (unsigned short)cA0[j];
            #pragma unroll
            for (int j = 0; j < 8; ++j) S[p][(b0 + 8 + j) * 72 + lane] = (unsigned short)cA1[j];
            // stage B (convert + write)
            {
                short8 p0, p1;
                p0[0] = (short)f2bf(cB0[0]); p0[1] = (short)f2bf(cB0[1]);
                p0[2] = (short)f2bf(cB0[2]); p0[3] = (short)f2bf(cB0[3]);
                p0[4] = (short)f2bf(cB1[0]); p0[5] = (short)f2bf(cB1[1]);
                p0[6] = (short)f2bf(cB1[2]); p0[7] = (short)f2bf(cB1[3]);
                p1[0] = (short)f2bf(cB2[0]); p1[1] = (short)f2bf(cB2[1]);
                p1[2] = (short)f2bf(cB2[2]); p1[3] = (short)f2bf(cB2[3]);
                p1[4] = (short)f2bf(cB3[0]); p1[5] = (short)f2bf(cB3[1]);
                p1[6] = (short)f2bf(cB3[2]); p1[7] = (short)f2bf(cB3[3]);
                unsigned short* bdst = &S[2 + p][o * 72 + kp * 16];
                *(short8*)bdst       = p0;
                *(short8*)(bdst + 8) = p1;
            }
            // own LDS writes visible, then barrier; do NOT drain vmcnt
            asm volatile("s_waitcnt lgkmcnt(0)" ::: "memory");
            __builtin_amdgcn_s_barrier();
            __builtin_amdgcn_sched_barrier(0);
            // MFMA phase
            #pragma unroll
            for (int ks = 0; ks < 2; ++ks) {
                int kof = ks * 32 + (lane >> 4) * 8;
                short8 a0 = *(const short8*)&S[p][(wm * 32 + (lane & 15)) * 72 + kof];
                short8 a1 = *(const short8*)&S[p][(wm * 32 + 16 + (lane & 15)) * 72 + kof];
                short8 q0 = *(const short8*)&S[2 + p][(wn * 32 + (lane & 15)) * 72 + kof];
                short8 q1 = *(const short8*)&S[2 + p][(wn * 32 + 16 + (lane & 15)) * 72 + kof];
                acc[li][0][0] = __builtin_amdgcn_mfma_f32_16x16x32_bf16(a0, q0, acc[li][0][0], 0, 0, 0);
                acc[li][0][1] = __builtin_amdgcn_mfma_f32_16x16x32_bf16(a0, q1, acc[li][0][1], 0, 0, 0);
                acc[li][1][0] = __builtin_amdgcn_mfma_f32_16x16x32_bf16(a1, q0, acc[li][1][0], 0, 0, 0);
                acc[li][1][1] = __builtin_amdgcn_mfma_f32_16x16x32_bf16(a1, q1, acc[li][1][1], 0, 0, 0);
            }
            cA0 = nA0; cA1 = nA1;
            cB0 = nB0; cB1 = nB1; cB2 = nB2; cB3 = nB3;
        }
    }

    // ---- epilogue: stage f32 tile [4096 rows][2 l] in LDS, then coalesced write ----
    __syncthreads();   // all MFMA LDS reads done before reuse
    float* F = (float*)S;
    const int col = lane & 15;
    const int rq  = (lane >> 4) * 4;
    #pragma unroll
    for (int j = 0; j < 2; ++j) {
        int n = wn * 32 + j * 16 + col;
        #pragma unroll
        for (int li = 0; li < 2; ++li) {
            float bv = bias[n * 1024 + l0 + li];
            #pragma unroll
            for (int i = 0; i < 2; ++i) {
                int mbase = wm * 32 + i * 16 + rq;
                #pragma unroll
                for (int q = 0; q < 4; ++q) {
                    F[((mbase + q) * 64 + n) * 2 + li] = acc[li][i][j][q] + bv;
                }
            }
        }
    }
    __syncthreads();
    #pragma unroll
    for (int i = 0; i < 16; ++i) {
        int r = t + i * 256;   // 0..4095 = b*64+o
        f32x2 v = *(const f32x2*)&F[r * 2];
        *(f32x2*)(out + (size_t)r * 1024 + l0) = v;
    }
}

// ---------------------------------------------------------------------------
// Fallback: naive direct conv (used only if ws_size too small)
// ---------------------------------------------------------------------------
__global__ __launch_bounds__(256) void k_naive(const float* __restrict__ x,
                                               const float* __restrict__ wgt,
                                               const float* __restrict__ bias,
                                               float* __restrict__ out) {
    int idx = blockIdx.x * 256 + threadIdx.x;
    int ow = idx & 31, oh = (idx >> 5) & 31, o = (idx >> 10) & 63, b = idx >> 16;
    float acc = bias[(o * 32 + oh) * 32 + ow];
    const float* wp = wgt + ((size_t)(oh * 32 + ow) * 64 + o) * 576;
    for (int c = 0; c < 64; ++c) {
        for (int kh = 0; kh < 3; ++kh) {
            int hh = oh + kh - 1;
            if ((unsigned)hh >= 32u) continue;
            for (int kw = 0; kw < 3; ++kw) {
                int ww = ow + kw - 1;
                if ((unsigned)ww >= 32u) continue;
                acc += x[((size_t)(b * 64 + c) * 32 + hh) * 32 + ww] * wp[c * 9 + kh * 3 + kw];
            }
        }
    }
    out[idx] = acc;
}

extern "C" void kernel_launch(void* const* d_in, const int* in_sizes, int n_in,
                              void* d_out, int out_size, void* d_ws, size_t ws_size,
                              hipStream_t stream) {
    const float* x    = (const float*)d_in[0];
    const float* wgt  = (const float*)d_in[1];
    const float* bias = (const float*)d_in[2];
    float* out = (float*)d_out;

    const size_t xt_bytes = (size_t)32 * 32 * 64 * 64 * 2;   // 8.39 MB

    if (ws_size >= xt_bytes) {
        unsigned short* xt = (unsigned short*)d_ws;
        k_xt<<<dim3(32, 8), 256, 0, stream>>>(x, xt);
        k_fused<<<512, 256, 0, stream>>>(wgt, xt, bias, out);
    } else {
        k_naive<<<(64 * 64 * 32 * 32) / 256, 256, 0, stream>>>(x, wgt, bias, out);
    }
}